// Round 3
// baseline (243.216 us; speedup 1.0000x reference)
//
#include <hip/hip_runtime.h>

#define BATCH 32
#define SEQ 512
#define CH4 96            // float4 per channel row (384 ch)
#define MAXL 4096
#define THREADS 256
#define SLABS 64          // phase-B blocks per batch; each owns 64 output rows
#define ROWS_PB 64        // MAXL / SLABS
#define ITERS 24          // ROWS_PB*CH4 / THREADS

typedef float v4f __attribute__((ext_vector_type(4)));
typedef int   v4i __attribute__((ext_vector_type(4)));

// R9: two-phase split to kill the per-block prologue + RFO theories.
// Both R6-scatter (95us est) and R8-gather (110us est) sit ~3x above the
// ~34us write roofline; candidate costs are (1) every block redoing
// scan+search (~0.8us serial head per block) and (2) L2 write-allocate
// fetching lines under the 202MB store stream (the 6.6TB/s fill shows
// FETCH~0 -- it doesn't pay this).
//
// Phase A (grid 256): per (batch, 1/8th of rows): shfl-scan the 512
//   durations (R6-proven), 10-step branchless searchsorted per row,
//   write idx map as raw ints INTO the out_mask buffer (exact size
//   match 32*4096*4B -- no workspace dependency).
// Phase B (grid 2048): fill-shaped streamer. Prologue = one 256B
//   coalesced idx read + barrier. 24 iters x 16B/lane gather from
//   L2-resident x, NONTEMPORAL 16B stores (no L2 allocation). Tail rows
//   (idx<0) store zero; real mask overwrites idx (same-thread program
//   order after the read -> safe).
__global__ __launch_bounds__(THREADS) void lr_index(
    const v4i* __restrict__ dur4,
    const int* __restrict__ max_len_p,
    int* __restrict__ idxbuf)
{
    __shared__ int s_end[SEQ];
    const int tid  = threadIdx.x;
    const int b    = blockIdx.x >> 3;      // 8 parts per batch
    const int part = blockIdx.x & 7;

    // --- wave-0 scan: 512 durations -> clipped inclusive ends (R6-proven) ---
    if (tid < 64) {
        const v4i* dp = dur4 + b * (SEQ / 4) + tid * 2;   // 8 ints/lane
        v4i d0 = dp[0], d1 = dp[1];
        int lane_sum = d0.x + d0.y + d0.z + d0.w + d1.x + d1.y + d1.z + d1.w;
        int incl = lane_sum;
        #pragma unroll
        for (int off = 1; off < 64; off <<= 1) {
            int v = __shfl_up(incl, off, 64);
            if (tid >= off) incl += v;
        }
        int cum = incl - lane_sum;                        // exclusive prefix
        const int maxlen = max_len_p[0];
        const int base = tid * 8;
        cum += d0.x; s_end[base + 0] = min(cum, maxlen);
        cum += d0.y; s_end[base + 1] = min(cum, maxlen);
        cum += d0.z; s_end[base + 2] = min(cum, maxlen);
        cum += d0.w; s_end[base + 3] = min(cum, maxlen);
        cum += d1.x; s_end[base + 4] = min(cum, maxlen);
        cum += d1.y; s_end[base + 5] = min(cum, maxlen);
        cum += d1.z; s_end[base + 6] = min(cum, maxlen);
        cum += d1.w; s_end[base + 7] = min(cum, maxlen);
    }
    __syncthreads();

    const int total = s_end[SEQ - 1];
    const int t0 = (part << 9) + tid;       // 512 rows per part, 2 per thread

    #pragma unroll
    for (int k = 0; k < 2; ++k) {
        const int t = t0 + (k << 8);
        // searchsorted(ends, t, 'right'): 10 = ceil(log2(513)) steps (R8 fix).
        int lo = 0, hi = SEQ;
        #pragma unroll
        for (int s = 0; s < 10; ++s) {
            int mid = (lo + hi) >> 1;
            mid = min(mid, SEQ - 1);
            const bool le = (s_end[mid] <= t);
            lo = le ? mid + 1 : lo;
            hi = le ? hi : mid;
        }
        idxbuf[(b << 12) + t] = (t < total) ? lo : -1;
    }
}

__global__ __launch_bounds__(THREADS) void lr_expand(
    const v4f* __restrict__ x,
    const int* idxbuf,          // aliases out_mask -- no restrict
    float* out_mask,
    v4f* __restrict__ out)
{
    __shared__ int s_src[ROWS_PB];
    const int tid  = threadIdx.x;
    const int bid  = blockIdx.x;
    const int b    = bid >> 6;             // SLABS = 64
    const int slab = bid & (SLABS - 1);
    const int r0   = slab * ROWS_PB;

    int myidx = 0;
    if (tid < ROWS_PB) {
        myidx = idxbuf[(b << 12) + r0 + tid];
        s_src[tid] = myidx;
        // same-thread read-then-write of the aliased cell: program order
        out_mask[(b << 12) + r0 + tid] = (myidx < 0) ? 1.0f : 0.0f;
    }
    __syncthreads();

    const v4f* xb = x + (size_t)b * (SEQ * CH4);
    v4f* ob = out + ((size_t)(b << 12) + r0) * CH4;
    const v4f vzero = (v4f){0.f, 0.f, 0.f, 0.f};

    #pragma unroll 6
    for (int it = 0; it < ITERS; ++it) {
        const int g = it * THREADS + tid;     // flat f4 index within slab
        const int r = g / CH4;                // compile-time magic-mul
        const int c = g - r * CH4;
        const int j = s_src[r];               // <=2 distinct per wave
        v4f v = vzero;
        if (j >= 0) v = xb[j * CH4 + c];
        __builtin_nontemporal_store(v, &ob[g]);  // 256 lanes x 16B contiguous
    }
}

extern "C" void kernel_launch(void* const* d_in, const int* in_sizes, int n_in,
                              void* d_out, int out_size, void* d_ws, size_t ws_size,
                              hipStream_t stream) {
    const v4f* x = (const v4f*)d_in[0];
    const v4i* dur4 = (const v4i*)d_in[1];
    const int* max_len_p = (const int*)d_in[2];
    float* out = (float*)d_out;
    float* out_mask = out + (size_t)BATCH * MAXL * CH4 * 4;

    lr_index<<<BATCH * 8, THREADS, 0, stream>>>(
        dur4, max_len_p, (int*)out_mask);
    lr_expand<<<BATCH * SLABS, THREADS, 0, stream>>>(
        x, (const int*)out_mask, out_mask, (v4f*)out);
}